// Round 1
// baseline (301.547 us; speedup 1.0000x reference)
//
#include <hip/hip_runtime.h>
#include <math.h>

typedef float  f32x4 __attribute__((ext_vector_type(4)));
typedef short  s16x8 __attribute__((ext_vector_type(8)));
typedef unsigned short u16x4 __attribute__((ext_vector_type(4)));

// ---------- helpers ----------
__device__ __forceinline__ unsigned short f2bf(float f) {
  unsigned u = __float_as_uint(f);
  u += 0x7FFFu + ((u >> 16) & 1u);   // round-to-nearest-even
  return (unsigned short)(u >> 16);
}
__device__ __forceinline__ float bf2f(unsigned short h) {
  return __uint_as_float(((unsigned)h) << 16);
}
// monotone float<->uint encoding for atomicMax on floats (incl. -inf)
__device__ __forceinline__ unsigned fenc(float f) {
  unsigned u = __float_as_uint(f);
  return (u & 0x80000000u) ? ~u : (u | 0x80000000u);
}
__device__ __forceinline__ float fdec(unsigned u) {
  u = (u & 0x80000000u) ? (u & 0x7FFFFFFFu) : ~u;
  return __uint_as_float(u);
}
__device__ __forceinline__ void gload16(const void* g, void* l) {
  __builtin_amdgcn_global_load_lds(
      (const __attribute__((address_space(1))) unsigned int*)g,
      (__attribute__((address_space(3))) unsigned int*)l, 16, 0, 0);
}

// ---------- f32 -> bf16 conversion (vectorized, grid-stride) ----------
__global__ __launch_bounds__(256) void cvt_kernel(const float* __restrict__ src,
                                                  unsigned short* __restrict__ dst,
                                                  int n4) {
  int i = blockIdx.x * 256 + threadIdx.x;
  int stride = gridDim.x * 256;
  for (; i < n4; i += stride) {
    f32x4 v = ((const f32x4*)src)[i];
    u16x4 o;
    o[0] = f2bf(v[0]); o[1] = f2bf(v[1]); o[2] = f2bf(v[2]); o[3] = f2bf(v[3]);
    ((u16x4*)dst)[i] = o;
  }
}

// ---------- GEMM: C[m][n] = bf16( sum_k A[m][k]*Bw[n][k] + bias[n] ) ----------
// A: [M][768] bf16, Bw: [N][768] bf16 (weight, row n contiguous in k), C: [M][768] bf16
__global__ __launch_bounds__(256) void gemm_bias(const unsigned short* __restrict__ A,
                                                 const unsigned short* __restrict__ Bw,
                                                 const float* __restrict__ bias,
                                                 unsigned short* __restrict__ C) {
  const int K = 768, LDC = 768;
  __shared__ __align__(16) unsigned short sA[128 * 64];
  __shared__ __align__(16) unsigned short sB[128 * 64];
  const int t = threadIdx.x;
  const int lane = t & 63, w = t >> 6;
  const int wr = w >> 1, wc = w & 1;
  const int m0 = blockIdx.x * 128;
  const int n0 = blockIdx.y * 128;
  const unsigned short* Ab = A + (size_t)m0 * K;
  const unsigned short* Bb = Bw + (size_t)n0 * K;
  f32x4 acc[4][4] = {};
  const int srow = t >> 3;          // 0..31
  const int scol = (t & 7) * 8;     // k-element offset within 64
  const int lg = lane >> 4, li = lane & 15;

  for (int k0 = 0; k0 < K; k0 += 64) {
#pragma unroll
    for (int s = 0; s < 4; ++s) {
      int row = srow + s * 32;
      gload16(Ab + (size_t)row * K + k0 + scol, (char*)sA + t * 16 + s * 4096);
      gload16(Bb + (size_t)row * K + k0 + scol, (char*)sB + t * 16 + s * 4096);
    }
    __syncthreads();
#pragma unroll
    for (int ks = 0; ks < 2; ++ks) {
      s16x8 af[4], bf_[4];
#pragma unroll
      for (int mi = 0; mi < 4; ++mi)
        af[mi] = *(const s16x8*)(sA + (wr * 64 + mi * 16 + li) * 64 + ks * 32 + lg * 8);
#pragma unroll
      for (int ni = 0; ni < 4; ++ni)
        bf_[ni] = *(const s16x8*)(sB + (wc * 64 + ni * 16 + li) * 64 + ks * 32 + lg * 8);
#pragma unroll
      for (int mi = 0; mi < 4; ++mi)
#pragma unroll
        for (int ni = 0; ni < 4; ++ni)
          acc[mi][ni] = __builtin_amdgcn_mfma_f32_16x16x32_bf16(af[mi], bf_[ni], acc[mi][ni], 0, 0, 0);
    }
    __syncthreads();
  }
  // epilogue: C/D layout col = lane&15, row = (lane>>4)*4 + reg  [m89-verified]
#pragma unroll
  for (int ni = 0; ni < 4; ++ni) {
    int col = n0 + wc * 64 + ni * 16 + li;
    float bv = bias[col];
#pragma unroll
    for (int mi = 0; mi < 4; ++mi) {
      int rbase = m0 + wr * 64 + mi * 16 + lg * 4;
#pragma unroll
      for (int r = 0; r < 4; ++r)
        C[(size_t)(rbase + r) * LDC + col] = f2bf(acc[mi][ni][r] + bv);
    }
  }
}

// ---------- row-normalize in place (one wave per 768-elem row) ----------
// rows 0..16383 -> Q, rows 16384..32767 -> Kt
__global__ __launch_bounds__(256) void rownorm(unsigned short* __restrict__ Q,
                                               unsigned short* __restrict__ Kt) {
  int row = blockIdx.x * 4 + (threadIdx.x >> 6);
  int lane = threadIdx.x & 63;
  unsigned short* base = (row < 16384) ? (Q + (size_t)row * 768)
                                       : (Kt + (size_t)(row - 16384) * 768);
  u16x4 d[3];
  float ss = 0.f;
#pragma unroll
  for (int j = 0; j < 3; ++j) {
    d[j] = *(const u16x4*)(base + (j * 64 + lane) * 4);
#pragma unroll
    for (int e = 0; e < 4; ++e) { float f = bf2f(d[j][e]); ss += f * f; }
  }
#pragma unroll
  for (int off = 1; off < 64; off <<= 1) ss += __shfl_xor(ss, off, 64);
  float scale = 1.0f / fmaxf(sqrtf(ss), 1e-8f);
#pragma unroll
  for (int j = 0; j < 3; ++j) {
    u16x4 o;
#pragma unroll
    for (int e = 0; e < 4; ++e) o[e] = f2bf(bf2f(d[j][e]) * scale);
    *(u16x4*)(base + (j * 64 + lane) * 4) = o;
  }
}

// ---------- init running-max buffer to enc(-inf) ----------
__global__ __launch_bounds__(256) void init_umax(unsigned* __restrict__ um, int n) {
  int i = blockIdx.x * 256 + threadIdx.x;
  if (i < n) um[i] = 0x007FFFFFu;  // fenc(-inf)
}

// ---------- scores block GEMM + masked row-max ----------
__global__ __launch_bounds__(256) void scores_max(const unsigned short* __restrict__ Qn,
                                                  const unsigned short* __restrict__ Kn,
                                                  const int* __restrict__ pad,
                                                  unsigned* __restrict__ umax) {
  const int K = 768;
  __shared__ __align__(16) unsigned short sA[128 * 64];
  __shared__ __align__(16) unsigned short sB[128 * 64];
  const int t = threadIdx.x;
  const int lane = t & 63, w = t >> 6;
  const int wr = w >> 1, wc = w & 1;
  const int qt = blockIdx.x, kt = blockIdx.y, b = blockIdx.z;
  const unsigned short* Ab = Qn + ((size_t)b * 1024 + qt * 128) * K;
  const unsigned short* Bb = Kn + ((size_t)b * 1024 + kt * 128) * K;
  f32x4 acc[4][4] = {};
  const int srow = t >> 3;
  const int scol = (t & 7) * 8;
  const int lg = lane >> 4, li = lane & 15;

  for (int k0 = 0; k0 < K; k0 += 64) {
#pragma unroll
    for (int s = 0; s < 4; ++s) {
      int row = srow + s * 32;
      gload16(Ab + (size_t)row * K + k0 + scol, (char*)sA + t * 16 + s * 4096);
      gload16(Bb + (size_t)row * K + k0 + scol, (char*)sB + t * 16 + s * 4096);
    }
    __syncthreads();
#pragma unroll
    for (int ks = 0; ks < 2; ++ks) {
      s16x8 af[4], bf_[4];
#pragma unroll
      for (int mi = 0; mi < 4; ++mi)
        af[mi] = *(const s16x8*)(sA + (wr * 64 + mi * 16 + li) * 64 + ks * 32 + lg * 8);
#pragma unroll
      for (int ni = 0; ni < 4; ++ni)
        bf_[ni] = *(const s16x8*)(sB + (wc * 64 + ni * 16 + li) * 64 + ks * 32 + lg * 8);
#pragma unroll
      for (int mi = 0; mi < 4; ++mi)
#pragma unroll
        for (int ni = 0; ni < 4; ++ni)
          acc[mi][ni] = __builtin_amdgcn_mfma_f32_16x16x32_bf16(af[mi], bf_[ni], acc[mi][ni], 0, 0, 0);
    }
    __syncthreads();
  }
  // epilogue: per-lane column is fixed per ni (col = lane&15 within frag)
  bool valid[4];
#pragma unroll
  for (int ni = 0; ni < 4; ++ni) {
    int col = kt * 128 + wc * 64 + ni * 16 + li;
    valid[ni] = (pad[b * 1024 + col] == 0);
  }
#pragma unroll
  for (int mi = 0; mi < 4; ++mi) {
#pragma unroll
    for (int r = 0; r < 4; ++r) {
      float v = -INFINITY;
#pragma unroll
      for (int ni = 0; ni < 4; ++ni)
        if (valid[ni]) v = fmaxf(v, acc[mi][ni][r]);
      // reduce over the 16 lanes holding this row's 16 columns
#pragma unroll
      for (int off = 1; off < 16; off <<= 1) v = fmaxf(v, __shfl_xor(v, off, 64));
      if (li == 0) {
        int row = b * 1024 + qt * 128 + wr * 64 + mi * 16 + lg * 4 + r;
        atomicMax(&umax[row], fenc(v));
      }
    }
  }
}

// ---------- tiny MLP: out = sigmoid(relu(m*W1+b1) @ W2 + b2) ----------
__global__ __launch_bounds__(256) void mlp_kernel(const unsigned* __restrict__ umax,
                                                  const float* __restrict__ w1,
                                                  const float* __restrict__ b1,
                                                  const float* __restrict__ w2,
                                                  const float* __restrict__ b2,
                                                  float* __restrict__ out, int n) {
  int i = blockIdx.x * 256 + threadIdx.x;
  if (i >= n) return;
  float m = fdec(umax[i]);
  float s = b2[0];
#pragma unroll
  for (int j = 0; j < 16; ++j) s += w2[j] * fmaxf(m * w1[j] + b1[j], 0.f);
  out[i] = 1.f / (1.f + expf(-s));
}

// ---------- host ----------
extern "C" void kernel_launch(void* const* d_in, const int* in_sizes, int n_in,
                              void* d_out, int out_size, void* d_ws, size_t ws_size,
                              hipStream_t stream) {
  const float* image = (const float*)d_in[0];   // [16,32,32,768]
  const float* text  = (const float*)d_in[1];   // [16,1024,768]
  const int*   pad   = (const int*)d_in[2];     // [16,32,32] bool->int
  const float* Wq    = (const float*)d_in[3];
  const float* bq    = (const float*)d_in[4];
  const float* Wk    = (const float*)d_in[5];
  const float* bk    = (const float*)d_in[6];
  const float* W1    = (const float*)d_in[7];
  const float* b1    = (const float*)d_in[8];
  const float* W2    = (const float*)d_in[9];
  const float* b2    = (const float*)d_in[10];
  float* out = (float*)d_out;

  char* ws = (char*)d_ws;
  unsigned short* Xb  = (unsigned short*)(ws);                 // 25165824 B (reused for text then image)
  unsigned short* Wqb = (unsigned short*)(ws + 25165824);      // 1179648 B
  unsigned short* Wkb = (unsigned short*)(ws + 26345472);      // 1179648 B
  unsigned short* Qh  = (unsigned short*)(ws + 27525120);      // 25165824 B
  unsigned short* Kh  = (unsigned short*)(ws + 52690944);      // 25165824 B
  unsigned*       um  = (unsigned*)(ws + 77856768);            // 65536 B

  const int NTEXT = 16 * 1024 * 768;   // 12582912
  const int NW    = 768 * 768;         // 589824

  // conversions
  {
    int n4 = NW >> 2; int blk = (n4 + 255) / 256;
    cvt_kernel<<<blk, 256, 0, stream>>>(Wq, Wqb, n4);
    cvt_kernel<<<blk, 256, 0, stream>>>(Wk, Wkb, n4);
  }
  {
    int n4 = NTEXT >> 2; int blk = 4096;
    cvt_kernel<<<blk, 256, 0, stream>>>(text, Xb, n4);
    // Q projection: M=16384, N=768
    gemm_bias<<<dim3(128, 6), 256, 0, stream>>>(Xb, Wqb, bq, Qh);
    cvt_kernel<<<blk, 256, 0, stream>>>(image, Xb, n4);
    gemm_bias<<<dim3(128, 6), 256, 0, stream>>>(Xb, Wkb, bk, Kh);
  }
  // normalize both in place (32768 rows, 4 rows/block)
  rownorm<<<8192, 256, 0, stream>>>(Qh, Kh);
  // init running max
  init_umax<<<64, 256, 0, stream>>>(um, 16384);
  // masked cosine scores + row max
  scores_max<<<dim3(8, 8, 16), 256, 0, stream>>>(Qh, Kh, pad, um);
  // tiny MLP
  mlp_kernel<<<64, 256, 0, stream>>>(um, W1, b1, W2, b2, out, 16384);
}

// Round 3
// 243.669 us; speedup vs baseline: 1.2375x; 1.2375x over previous
//
#include <hip/hip_runtime.h>
#include <math.h>

typedef float  f32x4 __attribute__((ext_vector_type(4)));
typedef short  s16x8 __attribute__((ext_vector_type(8)));
typedef unsigned short u16x4 __attribute__((ext_vector_type(4)));
typedef unsigned short u16x8 __attribute__((ext_vector_type(8)));

// ---------- helpers ----------
__device__ __forceinline__ unsigned short f2bf(float f) {
  unsigned u = __float_as_uint(f);
  u += 0x7FFFu + ((u >> 16) & 1u);   // round-to-nearest-even
  return (unsigned short)(u >> 16);
}
__device__ __forceinline__ float bf2f(unsigned short h) {
  return __uint_as_float(((unsigned)h) << 16);
}
// monotone float<->uint encoding for atomicMax on floats (incl. -inf)
__device__ __forceinline__ unsigned fenc(float f) {
  unsigned u = __float_as_uint(f);
  return (u & 0x80000000u) ? ~u : (u | 0x80000000u);
}
__device__ __forceinline__ float fdec(unsigned u) {
  u = (u & 0x80000000u) ? (u & 0x7FFFFFFFu) : ~u;
  return __uint_as_float(u);
}
__device__ __forceinline__ void gload16(const void* g, void* l) {
  __builtin_amdgcn_global_load_lds(
      (const __attribute__((address_space(1))) unsigned int*)g,
      (__attribute__((address_space(3))) unsigned int*)l, 16, 0, 0);
}

// ---------- init umax=-inf enc, ssq buffers = 0 ----------
__global__ __launch_bounds__(256) void init_bufs(unsigned* __restrict__ um,
                                                 float* __restrict__ qs,
                                                 float* __restrict__ ks, int n) {
  int i = blockIdx.x * 256 + threadIdx.x;
  if (i < n) { um[i] = 0x007FFFFFu; qs[i] = 0.f; ks[i] = 0.f; }
}

// ---------- weights f32 -> bf16 (both in one launch) ----------
__global__ __launch_bounds__(256) void cvt2(const float* __restrict__ a,
                                            const float* __restrict__ b,
                                            unsigned short* __restrict__ da,
                                            unsigned short* __restrict__ db, int n4) {
  int i = blockIdx.x * 256 + threadIdx.x;
  int stride = gridDim.x * 256;
  for (; i < 2 * n4; i += stride) {
    const float* s = (i < n4) ? a : b;
    unsigned short* d = (i < n4) ? da : db;
    int j = (i < n4) ? i : i - n4;
    f32x4 v = ((const f32x4*)s)[j];
    u16x4 o;
    o[0] = f2bf(v[0]); o[1] = f2bf(v[1]); o[2] = f2bf(v[2]); o[3] = f2bf(v[3]);
    ((u16x4*)d)[j] = o;
  }
}

// ---------- proj: Out = bf16(Xf32 @ W^T + bias), ssq[row] += (sum of squares) ----------
// blockIdx.z: 0 -> q (text), 1 -> k (image). A fused f32->bf16 reg-stage; B bf16 gload16.
// LDS layout swizzled: logical halfword khw of row stored at khw ^ ((row&7)<<3).
__global__ __launch_bounds__(256) void proj(const float* __restrict__ Xq,
                                            const float* __restrict__ Xk,
                                            const unsigned short* __restrict__ Wqb,
                                            const unsigned short* __restrict__ Wkb,
                                            const float* __restrict__ bq,
                                            const float* __restrict__ bk,
                                            unsigned short* __restrict__ Qh,
                                            unsigned short* __restrict__ Kh,
                                            float* __restrict__ qssq,
                                            float* __restrict__ kssq) {
  const int K = 768;
  __shared__ __align__(16) unsigned short sA[128 * 64];
  __shared__ __align__(16) unsigned short sB[128 * 64];
  // XCD-friendly remap: xcd = id&7 owns contiguous 16-tile row chunk; by varies fastest
  int id = blockIdx.x;                 // 0..767
  int xcd = id & 7, j = id >> 3;       // j: 0..95
  int by = j % 6, bxl = j / 6;         // by 0..5, bxl 0..15
  int bx = xcd * 16 + bxl;             // 0..127
  const float* A; const unsigned short* Bw; const float* bias;
  unsigned short* Out; float* ssq;
  if (blockIdx.z == 0) { A = Xq; Bw = Wqb; bias = bq; Out = Qh; ssq = qssq; }
  else                 { A = Xk; Bw = Wkb; bias = bk; Out = Kh; ssq = kssq; }

  const int t = threadIdx.x;
  const int lane = t & 63, w = t >> 6;
  const int wr = w >> 1, wc = w & 1;
  const int m0 = bx * 128, n0 = by * 128;
  const float* Ab = A + (size_t)m0 * K;
  const unsigned short* Bb = Bw + (size_t)n0 * K;
  f32x4 acc[4][4] = {};
  const int srow = t >> 3;             // 0..31
  const int scol = (t & 7) * 8;        // halfword col offset in 64
  const int hsw = scol ^ ((srow & 7) << 3);  // pre-swizzled source col
  const int lg = lane >> 4, li = lane & 15;

  for (int k0 = 0; k0 < K; k0 += 64) {
    // B: bf16 weights, global_load_lds with pre-swizzled source
#pragma unroll
    for (int s = 0; s < 4; ++s) {
      int row = srow + s * 32;
      gload16(Bb + (size_t)row * K + k0 + hsw, (char*)sB + t * 16 + s * 4096);
    }
    // A: f32 -> bf16 reg-stage, swizzled ds_write
#pragma unroll
    for (int s = 0; s < 4; ++s) {
      int row = srow + s * 32;
      const float* src = Ab + (size_t)row * K + k0 + scol;
      f32x4 v0 = *(const f32x4*)(src);
      f32x4 v1 = *(const f32x4*)(src + 4);
      u16x8 o;
      o[0] = f2bf(v0[0]); o[1] = f2bf(v0[1]); o[2] = f2bf(v0[2]); o[3] = f2bf(v0[3]);
      o[4] = f2bf(v1[0]); o[5] = f2bf(v1[1]); o[6] = f2bf(v1[2]); o[7] = f2bf(v1[3]);
      *(u16x8*)(sA + row * 64 + (scol ^ ((row & 7) << 3))) = o;
    }
    __syncthreads();
#pragma unroll
    for (int ks = 0; ks < 2; ++ks) {
      s16x8 af[4], bfr[4];
#pragma unroll
      for (int mi = 0; mi < 4; ++mi) {
        int row = wr * 64 + mi * 16 + li;
        af[mi] = *(const s16x8*)(sA + row * 64 + ((ks * 32 + lg * 8) ^ ((row & 7) << 3)));
      }
#pragma unroll
      for (int ni = 0; ni < 4; ++ni) {
        int row = wc * 64 + ni * 16 + li;
        bfr[ni] = *(const s16x8*)(sB + row * 64 + ((ks * 32 + lg * 8) ^ ((row & 7) << 3)));
      }
#pragma unroll
      for (int mi = 0; mi < 4; ++mi)
#pragma unroll
        for (int ni = 0; ni < 4; ++ni)
          acc[mi][ni] = __builtin_amdgcn_mfma_f32_16x16x32_bf16(af[mi], bfr[ni], acc[mi][ni], 0, 0, 0);
    }
    __syncthreads();
  }
  // epilogue: bias, bf16 store, per-row sum-of-squares (pre-rounding) -> atomicAdd
  float bv[4]; int col[4];
#pragma unroll
  for (int ni = 0; ni < 4; ++ni) { col[ni] = n0 + wc * 64 + ni * 16 + li; bv[ni] = bias[col[ni]]; }
#pragma unroll
  for (int mi = 0; mi < 4; ++mi) {
    int rbase = m0 + wr * 64 + mi * 16 + lg * 4;
#pragma unroll
    for (int r = 0; r < 4; ++r) {
      float s = 0.f;
#pragma unroll
      for (int ni = 0; ni < 4; ++ni) {
        float v = acc[mi][ni][r] + bv[ni];
        Out[(size_t)(rbase + r) * 768 + col[ni]] = f2bf(v);
        s += v * v;
      }
#pragma unroll
      for (int off = 1; off < 16; off <<= 1) s += __shfl_xor(s, off, 64);
      if (li == 0) atomicAdd(&ssq[rbase + r], s);
    }
  }
}

// ---------- scores: raw Q.K MFMA; epilogue scales by 1/||k||, masks, row-max ----------
__global__ __launch_bounds__(256) void scores_max(const unsigned short* __restrict__ Qh,
                                                  const unsigned short* __restrict__ Kh,
                                                  const float* __restrict__ kssq,
                                                  const int* __restrict__ pad,
                                                  unsigned* __restrict__ umax) {
  const int K = 768;
  __shared__ __align__(16) unsigned short sA[128 * 64];
  __shared__ __align__(16) unsigned short sB[128 * 64];
  // batch -> XCD mapping: id&7 == batch&7, so one batch's 3MB working set stays in one L2
  int id = blockIdx.x;                 // 0..1023
  int x = id & 7, g = id >> 3;         // g: 0..127
  int tile = g & 63;
  int qt = tile & 7, kt = tile >> 3;
  int b = ((g >> 6) << 3) | x;         // 0..15

  const int t = threadIdx.x;
  const int lane = t & 63, w = t >> 6;
  const int wr = w >> 1, wc = w & 1;
  const unsigned short* Ab = Qh + ((size_t)b * 1024 + qt * 128) * K;
  const unsigned short* Bb = Kh + ((size_t)b * 1024 + kt * 128) * K;
  f32x4 acc[4][4] = {};
  const int srow = t >> 3;
  const int scol = (t & 7) * 8;
  const int hsw = scol ^ ((srow & 7) << 3);
  const int lg = lane >> 4, li = lane & 15;

  for (int k0 = 0; k0 < K; k0 += 64) {
#pragma unroll
    for (int s = 0; s < 4; ++s) {
      int row = srow + s * 32;
      gload16(Ab + (size_t)row * K + k0 + hsw, (char*)sA + t * 16 + s * 4096);
      gload16(Bb + (size_t)row * K + k0 + hsw, (char*)sB + t * 16 + s * 4096);
    }
    __syncthreads();
#pragma unroll
    for (int ks = 0; ks < 2; ++ks) {
      s16x8 af[4], bfr[4];
#pragma unroll
      for (int mi = 0; mi < 4; ++mi) {
        int row = wr * 64 + mi * 16 + li;
        af[mi] = *(const s16x8*)(sA + row * 64 + ((ks * 32 + lg * 8) ^ ((row & 7) << 3)));
      }
#pragma unroll
      for (int ni = 0; ni < 4; ++ni) {
        int row = wc * 64 + ni * 16 + li;
        bfr[ni] = *(const s16x8*)(sB + row * 64 + ((ks * 32 + lg * 8) ^ ((row & 7) << 3)));
      }
#pragma unroll
      for (int mi = 0; mi < 4; ++mi)
#pragma unroll
        for (int ni = 0; ni < 4; ++ni)
          acc[mi][ni] = __builtin_amdgcn_mfma_f32_16x16x32_bf16(af[mi], bfr[ni], acc[mi][ni], 0, 0, 0);
    }
    __syncthreads();
  }
  // epilogue: per-column 1/max(||k||,eps) scaling, pad mask, row max, atomicMax
  float rk[4]; bool valid[4];
#pragma unroll
  for (int ni = 0; ni < 4; ++ni) {
    int gcol = b * 1024 + kt * 128 + wc * 64 + ni * 16 + li;
    rk[ni] = 1.0f / fmaxf(sqrtf(kssq[gcol]), 1e-8f);
    valid[ni] = (pad[gcol] == 0);
  }
#pragma unroll
  for (int mi = 0; mi < 4; ++mi) {
#pragma unroll
    for (int r = 0; r < 4; ++r) {
      float v = -INFINITY;
#pragma unroll
      for (int ni = 0; ni < 4; ++ni)
        if (valid[ni]) v = fmaxf(v, acc[mi][ni][r] * rk[ni]);
#pragma unroll
      for (int off = 1; off < 16; off <<= 1) v = fmaxf(v, __shfl_xor(v, off, 64));
      if (li == 0) {
        int row = b * 1024 + qt * 128 + wr * 64 + mi * 16 + lg * 4 + r;
        atomicMax(&umax[row], fenc(v));
      }
    }
  }
}

// ---------- tiny MLP: out = sigmoid(relu((max/||q||)*W1+b1) @ W2 + b2) ----------
__global__ __launch_bounds__(256) void mlp_kernel(const unsigned* __restrict__ umax,
                                                  const float* __restrict__ qssq,
                                                  const float* __restrict__ w1,
                                                  const float* __restrict__ b1,
                                                  const float* __restrict__ w2,
                                                  const float* __restrict__ b2,
                                                  float* __restrict__ out, int n) {
  int i = blockIdx.x * 256 + threadIdx.x;
  if (i >= n) return;
  float m = fdec(umax[i]) / fmaxf(sqrtf(qssq[i]), 1e-8f);
  float s = b2[0];
#pragma unroll
  for (int j = 0; j < 16; ++j) s += w2[j] * fmaxf(m * w1[j] + b1[j], 0.f);
  out[i] = 1.f / (1.f + expf(-s));
}

// ---------- host ----------
extern "C" void kernel_launch(void* const* d_in, const int* in_sizes, int n_in,
                              void* d_out, int out_size, void* d_ws, size_t ws_size,
                              hipStream_t stream) {
  const float* image = (const float*)d_in[0];   // [16,32,32,768]
  const float* text  = (const float*)d_in[1];   // [16,1024,768]
  const int*   pad   = (const int*)d_in[2];     // [16,32,32]
  const float* Wq    = (const float*)d_in[3];
  const float* bq    = (const float*)d_in[4];
  const float* Wk    = (const float*)d_in[5];
  const float* bk    = (const float*)d_in[6];
  const float* W1    = (const float*)d_in[7];
  const float* b1    = (const float*)d_in[8];
  const float* W2    = (const float*)d_in[9];
  const float* b2    = (const float*)d_in[10];
  float* out = (float*)d_out;

  char* ws = (char*)d_ws;
  unsigned short* Qh  = (unsigned short*)(ws);                 // 25165824 B
  unsigned short* Kh  = (unsigned short*)(ws + 25165824);      // 25165824 B
  unsigned short* Wqb = (unsigned short*)(ws + 50331648);      // 1179648 B
  unsigned short* Wkb = (unsigned short*)(ws + 51511296);      // 1179648 B
  unsigned*       um  = (unsigned*)(ws + 52690944);            // 65536 B
  float*          qss = (float*)(ws + 52756480);               // 65536 B
  float*          kss = (float*)(ws + 52822016);               // 65536 B

  init_bufs<<<64, 256, 0, stream>>>(um, qss, kss, 16384);
  cvt2<<<1152, 256, 0, stream>>>(Wq, Wk, Wqb, Wkb, 147456);
  proj<<<dim3(768, 1, 2), 256, 0, stream>>>(text, image, Wqb, Wkb, bq, bk, Qh, Kh, qss, kss);
  scores_max<<<1024, 256, 0, stream>>>(Qh, Kh, kss, pad, um);
  mlp_kernel<<<64, 256, 0, stream>>>(um, qss, W1, b1, W2, b2, out, 16384);
}